// Round 10
// baseline (271.979 us; speedup 1.0000x reference)
//
#include <hip/hip_runtime.h>
#include <math.h>

#define THREADS 256
#define TPW 8                  // 16-row tiles per wave (processed in pairs)
#define ROWS_PER_BLOCK 512     // 4 waves * TPW * 16
#define SROWS 4                // sampler: rows per thread
// bf16x3 (RTN) MFMA p-error <~2e-5 worst case; 2e-4 margin is ~10x safety.
#define P_MARGIN 2e-4f
#define FIXCAP 32

typedef float f32x4 __attribute__((ext_vector_type(4)));
typedef short short8 __attribute__((ext_vector_type(8)));
union Frag { unsigned u[4]; short8 s; };

// ---- LDS dword offsets (probs kernel) ----
#define FR1 0       // L1: K=32,N=64p:  4 tiles -> 2048 dw
#define FR2 2048    // L2: K=64p,N=32p: 2kt*2t  -> 2048 dw
#define FR3 4096    // L3: K=32p,N=32p: 2 tiles -> 1024 dw
#define FR4 5120    // L4: K=32p,N=32p: 2 tiles -> 1024 dw
#define FR5 6144    // L5: K=32p,N=16p: 1 tile  -> 512 dw (identity col map)
#define VB1 6656
#define VS1 6708
#define VE1 6760
#define VB2 6812
#define VS2 6844
#define VE2 6876
#define VB3 6908
#define VS3 6928
#define VE3 6948
#define VB4 6968
#define VB5 6984
#define PZ  6992    // 32 dw zero pad (absorbs padded-feature param reads)
#define WPOOL 7024  // 28096 B

// Exact JAX threefry2x32 (20 rounds, key schedule every 4), key = (0, 42).
__device__ __forceinline__ void tf2x32(unsigned x0, unsigned x1,
                                       unsigned &o0, unsigned &o1) {
  const unsigned k0 = 0u;
  const unsigned k1 = 42u;
  const unsigned k2 = 0x1BD11BDAu ^ k0 ^ k1;
  x0 += k0; x1 += k1;
#define TF_R(r) { x0 += x1; x1 = (x1 << (r)) | (x1 >> (32 - (r))); x1 ^= x0; }
  TF_R(13) TF_R(15) TF_R(26) TF_R(6)
  x0 += k1; x1 += k2 + 1u;
  TF_R(17) TF_R(29) TF_R(16) TF_R(24)
  x0 += k2; x1 += k0 + 2u;
  TF_R(13) TF_R(15) TF_R(26) TF_R(6)
  x0 += k0; x1 += k1 + 3u;
  TF_R(17) TF_R(29) TF_R(16) TF_R(24)
  x0 += k1; x1 += k2 + 4u;
  TF_R(13) TF_R(15) TF_R(26) TF_R(6)
  x0 += k2; x1 += k0 + 5u;
#undef TF_R
  o0 = x0; o1 = x1;
}

// bf16 round-to-nearest-even, result in top 16 bits (low 16 zero)
__device__ __forceinline__ unsigned rtnb(float v) {
  unsigned b = __float_as_uint(v);
  return (b + 0x7FFFu + ((b >> 16) & 1u)) & 0xFFFF0000u;
}

// v_cvt_pk_bf16_f32: dst = {bf16(a) low16, bf16(b) high16}, RTNE
__device__ __forceinline__ unsigned cvtpk(float a, float b) {
  unsigned r;
  asm("v_cvt_pk_bf16_f32 %0, %1, %2" : "=v"(r) : "v"(a), "v"(b));
  return r;
}

// Split 8 f32 (k-offsets 0..7) into hi/lo bf16x8 fragments (dword d={2d,2d+1})
__device__ __forceinline__ void pack8(const float f[8], short8 &H, short8 &L) {
  Frag h, l;
#pragma unroll
  for (int d = 0; d < 4; ++d) {
    unsigned hd = cvtpk(f[2 * d], f[2 * d + 1]);
    h.u[d] = hd;
    float r0 = f[2 * d]     - __uint_as_float(hd << 16);
    float r1 = f[2 * d + 1] - __uint_as_float(hd & 0xFFFF0000u);
    l.u[d] = cvtpk(r0, r1);
  }
  H = h.s; L = l.s;
}

__device__ __forceinline__ f32x4 mfma16(short8 a, short8 b, f32x4 c) {
  return __builtin_amdgcn_mfma_f32_16x16x32_bf16(a, b, c, 0, 0, 0);
}

__device__ __forceinline__ short8 ldfrag(const float *sW, int dwoff) {
  return *reinterpret_cast<const short8 *>(sW + dwoff);
}
__device__ __forceinline__ f32x4 ldv4(const float *sW, int dwoff) {
  return *reinterpret_cast<const f32x4 *>(sW + dwoff);
}

// Stage W as A-fragments of W^T (lane l: A[row=l&15][k=(l>>4)*8+e]).
// PERM: inner layers map out-feature n -> (tile, row) s.t. D regs chain
// lane-locally into the next layer's B-frag. Unstaged slots stay zero.
template <int K, int N, int NT, int FB, bool PERM>
__device__ __forceinline__ void stageA(const float *__restrict__ W,
                                       float *sW, int t) {
  for (int i = t; i < K * N; i += THREADS) {
    int k = i / N, n = i - k * N;
    float v = W[i];
    unsigned hb = rtnb(v);
    unsigned lb = rtnb(v - __uint_as_float(hb));
    int kt = k >> 5, g = (k >> 3) & 3, e = k & 7, d = e >> 1, par = e & 1;
    int tile, r;
    if (PERM) {
      int pg = n >> 5, m = n & 31, tt = (m >> 2) & 1;
      r = ((m >> 3) << 2) | (m & 3);
      tile = pg * 2 + tt;
    } else {
      tile = n >> 4; r = n & 15;
    }
    int lane = g * 16 + r;
    int dwhi = FB + (kt * NT + tile) * 512 + lane * 4 + d;
    unsigned short *hp = reinterpret_cast<unsigned short *>(sW);
    hp[2 * dwhi + par] = (unsigned short)(hb >> 16);
    hp[2 * (dwhi + 256) + par] = (unsigned short)(lb >> 16);
  }
}

// BN+ReLU two acc tiles (t0,t1 of one 32-feature pg) and pack to B-frag.
__device__ __forceinline__ void bnpack(f32x4 a0, f32x4 a1, const float *sW,
                                       int vs, int ve, int g,
                                       short8 &H, short8 &L) {
  f32x4 sc0 = ldv4(sW, vs + g * 8),     of0 = ldv4(sW, ve + g * 8);
  f32x4 sc1 = ldv4(sW, vs + g * 8 + 4), of1 = ldv4(sW, ve + g * 8 + 4);
  float f[8];
#pragma unroll
  for (int q = 0; q < 4; ++q) {
    f[q]     = fmaxf(fmaf(a0[q], sc0[q], of0[q]), 0.f);
    f[4 + q] = fmaxf(fmaf(a1[q], sc1[q], of1[q]), 0.f);
  }
  pack8(f, H, L);
}

// ============ KERNEL 1: probs (MFMA chain -> p, nothing else) ============
// Unchanged from R9 (it dropped below every prior monolith's duration).
__global__ __launch_bounds__(THREADS, 2)
void probs_kernel(const float* __restrict__ events,
                  const float* __restrict__ W1, const float* __restrict__ b1,
                  const float* __restrict__ g1, const float* __restrict__ be1,
                  const float* __restrict__ W2, const float* __restrict__ b2,
                  const float* __restrict__ g2, const float* __restrict__ be2,
                  const float* __restrict__ W3, const float* __restrict__ b3,
                  const float* __restrict__ g3, const float* __restrict__ be3,
                  const float* __restrict__ W4, const float* __restrict__ b4,
                  const float* __restrict__ W5, const float* __restrict__ b5,
                  float* __restrict__ outP, int B) {
  __shared__ float sW[WPOOL];

  const int t = threadIdx.x;
  const float rden = (float)(1.0 / sqrt(1.0 + 1e-5));

  for (int i = t; i < WPOOL; i += THREADS) sW[i] = 0.f;
  __syncthreads();
  stageA<32, 50, 4, FR1, true>(W1, sW, t);
  stageA<50, 30, 2, FR2, true>(W2, sW, t);
  stageA<30, 20, 2, FR3, true>(W3, sW, t);
  stageA<20, 15, 2, FR4, true>(W4, sW, t);
  stageA<15,  8, 1, FR5, false>(W5, sW, t);
  if (t < 50)                  { sW[VB1 + t] = b1[t]; sW[VS1 + t] = g1[t] * rden; sW[VE1 + t] = be1[t]; }
  else if (t >= 64 && t < 94)  { int i = t - 64;  sW[VB2 + i] = b2[i]; sW[VS2 + i] = g2[i] * rden; sW[VE2 + i] = be2[i]; }
  else if (t >= 128 && t < 148){ int i = t - 128; sW[VB3 + i] = b3[i]; sW[VS3 + i] = g3[i] * rden; sW[VE3 + i] = be3[i]; }
  else if (t >= 192 && t < 207){ sW[VB4 + (t - 192)] = b4[t - 192]; }
  else if (t >= 224 && t < 232){ sW[VB5 + (t - 224)] = b5[t - 224]; }
  __syncthreads();

  const int w = t >> 6, lane = t & 63;
  const int c = lane & 15, g = lane >> 4;
  const int labase = lane * 4;

  const int wrow0 = blockIdx.x * ROWS_PER_BLOCK + w * (TPW * 16);
  const float4 *xp = reinterpret_cast<const float4 *>(
      events + (size_t)(wrow0 + c) * 32 + g * 8);
  float4 xA0 = xp[0], xA1 = xp[1], xB0 = xp[128], xB1 = xp[129];

#pragma unroll 1
  for (int it = 0; it < TPW / 2; ++it) {
    const int rA = wrow0 + it * 32;
    const int rB = rA + 16;

    short8 Xh[2], Xl[2];
    {
      float fA[8] = {xA0.x, xA0.y, xA0.z, xA0.w, xA1.x, xA1.y, xA1.z, xA1.w};
      float fB[8] = {xB0.x, xB0.y, xB0.z, xB0.w, xB1.x, xB1.y, xB1.z, xB1.w};
      pack8(fA, Xh[0], Xl[0]);
      pack8(fB, Xh[1], Xl[1]);
    }
    {
      const int nit = (it + 1 < TPW / 2) ? it + 1 : it;
      const int nx = nit * 256;
      xA0 = xp[nx]; xA1 = xp[nx + 1]; xB0 = xp[nx + 128]; xB1 = xp[nx + 129];
    }

    // ---- L1 ----
    f32x4 a1[2][4];
#pragma unroll
    for (int ti = 0; ti < 4; ++ti) {
      short8 wh = ldfrag(sW, FR1 + ti * 512 + labase);
      short8 wl = ldfrag(sW, FR1 + ti * 512 + 256 + labase);
      f32x4 bias = ldv4(sW, VB1 + (ti >> 1) * 32 + g * 8 + (ti & 1) * 4);
#pragma unroll
      for (int u = 0; u < 2; ++u) {
        f32x4 acc = bias;
        acc = mfma16(wh, Xl[u], acc);
        acc = mfma16(wl, Xh[u], acc);
        a1[u][ti] = mfma16(wh, Xh[u], acc);
      }
    }

    short8 B2h[2][2], B2l[2][2];
#pragma unroll
    for (int u = 0; u < 2; ++u) {
      bnpack(a1[u][0], a1[u][1], sW, VS1,      VE1,      g, B2h[u][0], B2l[u][0]);
      bnpack(a1[u][2], a1[u][3], sW, VS1 + 32, VE1 + 32, g, B2h[u][1], B2l[u][1]);
    }

    // ---- L2 ----
    f32x4 a2[2][2];
#pragma unroll
    for (int u = 0; u < 2; ++u) {
      a2[u][0] = ldv4(sW, VB2 + g * 8);
      a2[u][1] = ldv4(sW, VB2 + g * 8 + 4);
    }
#pragma unroll
    for (int ti = 0; ti < 2; ++ti) {
#pragma unroll
      for (int kt = 0; kt < 2; ++kt) {
        short8 wh = ldfrag(sW, FR2 + (kt * 2 + ti) * 512 + labase);
        short8 wl = ldfrag(sW, FR2 + (kt * 2 + ti) * 512 + 256 + labase);
#pragma unroll
        for (int u = 0; u < 2; ++u) {
          a2[u][ti] = mfma16(wh, B2l[u][kt], a2[u][ti]);
          a2[u][ti] = mfma16(wl, B2h[u][kt], a2[u][ti]);
          a2[u][ti] = mfma16(wh, B2h[u][kt], a2[u][ti]);
        }
      }
    }

    short8 B3h[2], B3l[2];
#pragma unroll
    for (int u = 0; u < 2; ++u)
      bnpack(a2[u][0], a2[u][1], sW, VS2, VE2, g, B3h[u], B3l[u]);

    // ---- L3 ----
    f32x4 a3[2][2];
#pragma unroll
    for (int ti = 0; ti < 2; ++ti) {
      short8 wh = ldfrag(sW, FR3 + ti * 512 + labase);
      short8 wl = ldfrag(sW, FR3 + ti * 512 + 256 + labase);
      f32x4 bias = ldv4(sW, VB3 + g * 8 + ti * 4);
#pragma unroll
      for (int u = 0; u < 2; ++u) {
        f32x4 acc = bias;
        acc = mfma16(wh, B3l[u], acc);
        acc = mfma16(wl, B3h[u], acc);
        a3[u][ti] = mfma16(wh, B3h[u], acc);
      }
    }

    short8 B4h[2], B4l[2];
#pragma unroll
    for (int u = 0; u < 2; ++u)
      bnpack(a3[u][0], a3[u][1], sW, VS3, VE3, g, B4h[u], B4l[u]);

    // ---- L4 ----
    f32x4 a4[2][2];
#pragma unroll
    for (int ti = 0; ti < 2; ++ti) {
      short8 wh = ldfrag(sW, FR4 + ti * 512 + labase);
      short8 wl = ldfrag(sW, FR4 + ti * 512 + 256 + labase);
      f32x4 bias = ldv4(sW, VB4 + g * 8 + ti * 4);
#pragma unroll
      for (int u = 0; u < 2; ++u) {
        f32x4 acc = bias;
        acc = mfma16(wh, B4l[u], acc);
        acc = mfma16(wl, B4h[u], acc);
        a4[u][ti] = mfma16(wh, B4h[u], acc);
      }
    }

    short8 B5h[2], B5l[2];
#pragma unroll
    for (int u = 0; u < 2; ++u) {
      float f[8];
#pragma unroll
      for (int q = 0; q < 4; ++q) {
        f[q]     = fmaxf(a4[u][0][q], 0.f);
        f[4 + q] = fmaxf(a4[u][1][q], 0.f);
      }
      pack8(f, B5h[u], B5l[u]);
    }

    // ---- L5 ----
    f32x4 a5[2];
    {
      short8 wh = ldfrag(sW, FR5 + labase);
      short8 wl = ldfrag(sW, FR5 + 256 + labase);
      f32x4 bias = ldv4(sW, VB5 + g * 4);
#pragma unroll
      for (int u = 0; u < 2; ++u) {
        f32x4 acc = bias;
        acc = mfma16(wh, B5l[u], acc);
        acc = mfma16(wl, B5h[u], acc);
        a5[u] = mfma16(wh, B5h[u], acc);
      }
    }

    // ---- store p: every lane one float4 ----
    {
      f32x4 sw1;
#pragma unroll
      for (int q = 0; q < 4; ++q) sw1[q] = __shfl_xor(a5[1][q], 32);
      f32x4 src = (g < 2) ? a5[0] : sw1;
      const int row = ((g < 2) ? rA : rB) + c;
      float4 pv;
      pv.x = 1.f / (1.f + __expf(-src[0]));
      pv.y = 1.f / (1.f + __expf(-src[1]));
      pv.z = 1.f / (1.f + __expf(-src[2]));
      pv.w = 1.f / (1.f + __expf(-src[3]));
      *reinterpret_cast<float4 *>(outP + (size_t)row * 8 + (g & 1) * 4) = pv;
    }
  }
}

// ============ KERNEL 2: sample + margin repair (streaming) ============
// R9->R10: 4 rows/thread (8 independent float4 load chains issued up front
// -> MLP via ILP), p read from pbuf (workspace when it fits: out_chosen
// becomes write-only full lines, no cross-XCD dirty-line bounce).
__global__ __launch_bounds__(THREADS, 8)
void sample_kernel(const float* __restrict__ events,
                   const float* __restrict__ W1, const float* __restrict__ b1,
                   const float* __restrict__ g1, const float* __restrict__ be1,
                   const float* __restrict__ W2, const float* __restrict__ b2,
                   const float* __restrict__ g2, const float* __restrict__ be2,
                   const float* __restrict__ W3, const float* __restrict__ b3,
                   const float* __restrict__ g3, const float* __restrict__ be3,
                   const float* __restrict__ W4, const float* __restrict__ b4,
                   const float* __restrict__ W5, const float* __restrict__ b5,
                   const float* __restrict__ pbuf,
                   float* __restrict__ out_chosen,
                   float* __restrict__ out_logp, int B) {
  __shared__ unsigned s_cnt;
  __shared__ unsigned s_rows[FIXCAP];
  __shared__ double sA[64];
  __shared__ double sB[64];
  __shared__ double sF[8];

  const int t = threadIdx.x;
  if (t == 0) s_cnt = 0;
  __syncthreads();

  const int b0 = blockIdx.x * (THREADS * SROWS) + t;
  if (b0 < B) {  // B % (THREADS*SROWS) == 0 here; per-row guards below anyway
    // issue all loads up front (8 independent chains)
    float4 pv[SROWS][2];
#pragma unroll
    for (int rr = 0; rr < SROWS; ++rr) {
      const int b = b0 + rr * THREADS;
      const float4 *ps = reinterpret_cast<const float4 *>(pbuf + (size_t)b * 8);
      pv[rr][0] = ps[0];
      pv[rr][1] = ps[1];
    }

#pragma unroll
    for (int rr = 0; rr < SROWS; ++rr) {
      const int b = b0 + rr * THREADS;
      if (b >= B) continue;
      float p[8] = {pv[rr][0].x, pv[rr][0].y, pv[rr][0].z, pv[rr][0].w,
                    pv[rr][1].x, pv[rr][1].y, pv[rr][1].z, pv[rr][1].w};
      bool need = false;
      float prod = 1.f;
      float ch[8];
#pragma unroll
      for (int w = 0; w < 8; ++w) {
        unsigned j = 8u * (unsigned)b + (unsigned)w, o0, o1;
        tf2x32(0u, j, o0, o1);
        unsigned bits = o0 ^ o1;
        float u = __uint_as_float(0x3F800000u | (bits >> 9)) - 1.f;
        float thr = 1.f - p[w];
        bool choice = u < thr;
        need = need || (fabsf(u - thr) < P_MARGIN);
        ch[w] = choice ? 0.f : 1.f;
        prod *= choice ? thr : p[w];
      }
      if (need) {
        unsigned i = atomicAdd(&s_cnt, 1u);
        if (i < FIXCAP) s_rows[i] = (unsigned)b;
      }
      float4 *oc = reinterpret_cast<float4 *>(out_chosen + (size_t)b * 8);
      oc[0] = make_float4(ch[0], ch[1], ch[2], ch[3]);
      oc[1] = make_float4(ch[4], ch[5], ch[6], ch[7]);
      out_logp[b] = __logf(prod);
    }
  }

  // ---- block-cooperative fp64 repair of flagged rows (overwrites) ----
  __syncthreads();
  unsigned cnt = s_cnt;
  if (cnt > FIXCAP) cnt = FIXCAP;
  if (cnt == 0) return;

  const double denom = sqrt(1.0 + 1e-5);
  for (unsigned r = 0; r < cnt; ++r) {  // cnt is block-uniform
    const int rb = (int)s_rows[r];

    if (t < 32) sA[t] = (double)events[(size_t)rb * 32 + t];
    __syncthreads();

    double v = 0.0;
    if (t < 50) {
#pragma unroll
      for (int k = 0; k < 32; ++k) v = fma(sA[k], (double)W1[k * 50 + t], v);
      v += (double)b1[t];
      v = v * ((double)g1[t] / denom) + (double)be1[t];
      v = v > 0.0 ? v : 0.0;
    }
    __syncthreads();
    if (t < 50) sB[t] = v;
    __syncthreads();

    v = 0.0;
    if (t < 30) {
#pragma unroll
      for (int k = 0; k < 50; ++k) v = fma(sB[k], (double)W2[k * 30 + t], v);
      v += (double)b2[t];
      v = v * ((double)g2[t] / denom) + (double)be2[t];
      v = v > 0.0 ? v : 0.0;
    }
    __syncthreads();
    if (t < 30) sA[t] = v;
    __syncthreads();

    v = 0.0;
    if (t < 20) {
#pragma unroll
      for (int k = 0; k < 30; ++k) v = fma(sA[k], (double)W3[k * 20 + t], v);
      v += (double)b3[t];
      v = v * ((double)g3[t] / denom) + (double)be3[t];
      v = v > 0.0 ? v : 0.0;
    }
    __syncthreads();
    if (t < 20) sB[t] = v;
    __syncthreads();

    v = 0.0;
    if (t < 15) {
#pragma unroll
      for (int k = 0; k < 20; ++k) v = fma(sB[k], (double)W4[k * 15 + t], v);
      v += (double)b4[t];
      v = v > 0.0 ? v : 0.0;
    }
    __syncthreads();
    if (t < 15) sA[t] = v;
    __syncthreads();

    if (t < 8) {
      v = 0.0;
#pragma unroll
      for (int k = 0; k < 15; ++k) v = fma(sA[k], (double)W5[k * 8 + t], v);
      v += (double)b5[t];
      double p = 1.0 / (1.0 + exp(-v));
      unsigned j = 8u * (unsigned)rb + (unsigned)t, o0, o1;
      tf2x32(0u, j, o0, o1);
      unsigned bits = o0 ^ o1;
      float u = __uint_as_float(0x3F800000u | (bits >> 9)) - 1.f;
      double thr = 1.0 - p;
      bool choice = ((double)u < thr);
      out_chosen[(size_t)rb * 8 + t] = choice ? 0.f : 1.f;
      sF[t] = choice ? thr : p;
    }
    __syncthreads();
    if (t == 0) {
      double prod = 1.0;
      for (int w2 = 0; w2 < 8; ++w2) prod *= sF[w2];
      out_logp[rb] = (float)log(prod);
    }
    __syncthreads();
  }
}

extern "C" void kernel_launch(void* const* d_in, const int* in_sizes, int n_in,
                              void* d_out, int out_size, void* d_ws, size_t ws_size,
                              hipStream_t stream) {
  const float* events = (const float*)d_in[0];
  const float* W1  = (const float*)d_in[1];
  const float* b1  = (const float*)d_in[2];
  const float* g1  = (const float*)d_in[3];
  const float* be1 = (const float*)d_in[4];
  const float* W2  = (const float*)d_in[5];
  const float* b2  = (const float*)d_in[6];
  const float* g2  = (const float*)d_in[7];
  const float* be2 = (const float*)d_in[8];
  const float* W3  = (const float*)d_in[9];
  const float* b3  = (const float*)d_in[10];
  const float* g3  = (const float*)d_in[11];
  const float* be3 = (const float*)d_in[12];
  const float* W4  = (const float*)d_in[13];
  const float* b4  = (const float*)d_in[14];
  const float* W5  = (const float*)d_in[15];
  const float* b5  = (const float*)d_in[16];

  const int B = in_sizes[0] / 32;  // 524288
  float* out = (float*)d_out;
  float* out_chosen = out;                   // (B, 8)
  float* out_logp   = out + (size_t)B * 8;   // (B,)

  // p lives in workspace when it fits (write-only out_chosen, no dirty
  // cross-XCD bounce); fallback: in-place via out_chosen (R9 behavior).
  const size_t pbytes = (size_t)B * 8 * sizeof(float);
  float* pbuf = (ws_size >= pbytes) ? (float*)d_ws : out_chosen;

  const int blocks1 = (B + ROWS_PER_BLOCK - 1) / ROWS_PER_BLOCK;  // 1024
  hipLaunchKernelGGL(probs_kernel, dim3(blocks1), dim3(THREADS), 0, stream,
                     events, W1, b1, g1, be1, W2, b2, g2, be2,
                     W3, b3, g3, be3, W4, b4, W5, b5,
                     pbuf, B);

  const int blocks2 = (B + THREADS * SROWS - 1) / (THREADS * SROWS);  // 512
  hipLaunchKernelGGL(sample_kernel, dim3(blocks2), dim3(THREADS), 0, stream,
                     events, W1, b1, g1, be1, W2, b2, g2, be2,
                     W3, b3, g3, be3, W4, b4, W5, b5,
                     pbuf, out_chosen, out_logp, B);
}

// Round 11
// 216.093 us; speedup vs baseline: 1.2586x; 1.2586x over previous
//
#include <hip/hip_runtime.h>
#include <math.h>

#define THREADS 256
#define TPW 4                  // 16-row tiles per wave (fully unrolled)
#define ROWS_PER_BLOCK 256     // 4 waves * TPW * 16
// bf16x3 (RTN) MFMA p-error <~2e-5 worst case; 2e-4 margin is ~10x safety.
#define P_MARGIN 2e-4f
#define FIXCAP 64

typedef float f32x4 __attribute__((ext_vector_type(4)));
typedef short short8 __attribute__((ext_vector_type(8)));
union Frag { unsigned u[4]; short8 s; };

// ---- LDS dword offsets ----
// Weight A-fragments (W^T, bf16 hi/lo), entry dword =
//   FB + (combo*2 + hilo)*256 + lane*4 + d,  combo = kt*NT + tile
// Inner layers' out-features are PERMUTED into tiles so that the D result of
// layer L is, lane-locally, the B-fragment of layer L+1:
//   tile t, row r  <->  feature (r>>2)*8 + (r&3) + t*4   (within a 32-feat pg)
#define FR1 0       // L1: K=32,N=64p:  4 tiles -> 2048 dw
#define FR2 2048    // L2: K=64p,N=32p: 2kt*2t  -> 2048 dw
#define FR3 4096    // L3: K=32p,N=32p: 2 tiles -> 1024 dw
#define FR4 5120    // L4: K=32p,N=32p: 2 tiles -> 1024 dw
#define FR5 6144    // L5: K=32p,N=16p: 1 tile  -> 512 dw (identity col map)
#define VB1 6656
#define VS1 6708
#define VE1 6760
#define VB2 6812
#define VS2 6844
#define VE2 6876
#define VB3 6908
#define VS3 6928
#define VE3 6948
#define VB4 6968
#define VB5 6984
#define PZ  6992    // 32 dw zero pad (absorbs padded-feature param reads)
#define WPOOL 7024  // 28096 B

// Exact JAX threefry2x32 (20 rounds, key schedule every 4), key = (0, 42).
__device__ __forceinline__ void tf2x32(unsigned x0, unsigned x1,
                                       unsigned &o0, unsigned &o1) {
  const unsigned k0 = 0u;
  const unsigned k1 = 42u;
  const unsigned k2 = 0x1BD11BDAu ^ k0 ^ k1;
  x0 += k0; x1 += k1;
#define TF_R(r) { x0 += x1; x1 = (x1 << (r)) | (x1 >> (32 - (r))); x1 ^= x0; }
  TF_R(13) TF_R(15) TF_R(26) TF_R(6)
  x0 += k1; x1 += k2 + 1u;
  TF_R(17) TF_R(29) TF_R(16) TF_R(24)
  x0 += k2; x1 += k0 + 2u;
  TF_R(13) TF_R(15) TF_R(26) TF_R(6)
  x0 += k0; x1 += k1 + 3u;
  TF_R(17) TF_R(29) TF_R(16) TF_R(24)
  x0 += k1; x1 += k2 + 4u;
  TF_R(13) TF_R(15) TF_R(26) TF_R(6)
  x0 += k2; x1 += k0 + 5u;
#undef TF_R
  o0 = x0; o1 = x1;
}

// bf16 round-to-nearest-even, result in top 16 bits (low 16 zero)
__device__ __forceinline__ unsigned rtnb(float v) {
  unsigned b = __float_as_uint(v);
  return (b + 0x7FFFu + ((b >> 16) & 1u)) & 0xFFFF0000u;
}

// v_cvt_pk_bf16_f32: dst = {bf16(a) low16, bf16(b) high16}, RTNE
__device__ __forceinline__ unsigned cvtpk(float a, float b) {
  unsigned r;
  asm("v_cvt_pk_bf16_f32 %0, %1, %2" : "=v"(r) : "v"(a), "v"(b));
  return r;
}

// Split 8 f32 (k-offsets 0..7) into hi/lo bf16x8 fragments (dword d={2d,2d+1})
__device__ __forceinline__ void pack8(const float f[8], short8 &H, short8 &L) {
  Frag h, l;
#pragma unroll
  for (int d = 0; d < 4; ++d) {
    unsigned hd = cvtpk(f[2 * d], f[2 * d + 1]);
    h.u[d] = hd;
    float r0 = f[2 * d]     - __uint_as_float(hd << 16);
    float r1 = f[2 * d + 1] - __uint_as_float(hd & 0xFFFF0000u);
    l.u[d] = cvtpk(r0, r1);
  }
  H = h.s; L = l.s;
}

__device__ __forceinline__ f32x4 mfma16(short8 a, short8 b, f32x4 c) {
  return __builtin_amdgcn_mfma_f32_16x16x32_bf16(a, b, c, 0, 0, 0);
}

__device__ __forceinline__ short8 ldfrag(const float *sW, int dwoff) {
  return *reinterpret_cast<const short8 *>(sW + dwoff);
}
__device__ __forceinline__ f32x4 ldv4(const float *sW, int dwoff) {
  return *reinterpret_cast<const f32x4 *>(sW + dwoff);
}

// Stage W as A-fragments of W^T (lane l: A[row=l&15][k=(l>>4)*8+e]).
// PERM: inner layers map out-feature n -> (tile, row) s.t. D regs chain
// lane-locally into the next layer's B-frag. Unstaged slots stay zero.
template <int K, int N, int NT, int FB, bool PERM>
__device__ __forceinline__ void stageA(const float *__restrict__ W,
                                       float *sW, int t) {
  for (int i = t; i < K * N; i += THREADS) {
    int k = i / N, n = i - k * N;
    float v = W[i];
    unsigned hb = rtnb(v);
    unsigned lb = rtnb(v - __uint_as_float(hb));
    int kt = k >> 5, g = (k >> 3) & 3, e = k & 7, d = e >> 1, par = e & 1;
    int tile, r;
    if (PERM) {
      int pg = n >> 5, m = n & 31, tt = (m >> 2) & 1;
      r = ((m >> 3) << 2) | (m & 3);
      tile = pg * 2 + tt;
    } else {
      tile = n >> 4; r = n & 15;
    }
    int lane = g * 16 + r;
    int dwhi = FB + (kt * NT + tile) * 512 + lane * 4 + d;
    unsigned short *hp = reinterpret_cast<unsigned short *>(sW);
    hp[2 * dwhi + par] = (unsigned short)(hb >> 16);
    hp[2 * (dwhi + 256) + par] = (unsigned short)(lb >> 16);
  }
}

// BN+ReLU two acc tiles (t0,t1 of one 32-feature pg) and pack to B-frag.
__device__ __forceinline__ void bnpack(f32x4 a0, f32x4 a1, const float *sW,
                                       int vs, int ve, int g,
                                       short8 &H, short8 &L) {
  f32x4 sc0 = ldv4(sW, vs + g * 8),     of0 = ldv4(sW, ve + g * 8);
  f32x4 sc1 = ldv4(sW, vs + g * 8 + 4), of1 = ldv4(sW, ve + g * 8 + 4);
  float f[8];
#pragma unroll
  for (int q = 0; q < 4; ++q) {
    f[q]     = fmaxf(fmaf(a0[q], sc0[q], of0[q]), 0.f);
    f[4 + q] = fmaxf(fmaf(a1[q], sc1[q], of1[q]), 0.f);
  }
  pack8(f, H, L);
}

// R10->R11: back to the single monolith (the split added a 16MB p
// round-trip + a second dispatch for net loss). Change vs R7: the logits
// of all TPW tiles are kept in registers (aa[4], statically indexed via
// full unroll) and the ENTIRE sampling epilogue (shfl redistribute,
// sigmoid, threefry, stores) runs once after the tile loop. The 8
// independent threefry chains batch with high ILP, and the pure-VALU
// epilogue of one wave overlaps other waves' MFMA/LDS phases on the SIMD
// -- instead of serializing inside every tile iteration (R7/R8, 122us).
// Per-value numerics identical to R7 (ops reordered across independent
// values only).
__global__ __launch_bounds__(THREADS, 2)
void wtf_kernel(const float* __restrict__ events,
                const float* __restrict__ W1, const float* __restrict__ b1,
                const float* __restrict__ g1, const float* __restrict__ be1,
                const float* __restrict__ W2, const float* __restrict__ b2,
                const float* __restrict__ g2, const float* __restrict__ be2,
                const float* __restrict__ W3, const float* __restrict__ b3,
                const float* __restrict__ g3, const float* __restrict__ be3,
                const float* __restrict__ W4, const float* __restrict__ b4,
                const float* __restrict__ W5, const float* __restrict__ b5,
                float* __restrict__ out_chosen,
                float* __restrict__ out_logp,
                int B) {
  __shared__ float sW[WPOOL];
  __shared__ unsigned s_cnt;
  __shared__ unsigned s_rows[FIXCAP];
  __shared__ double sA[64];
  __shared__ double sB[64];
  __shared__ double sF[8];

  const int t = threadIdx.x;
  const float rden = (float)(1.0 / sqrt(1.0 + 1e-5));

  if (t == 0) s_cnt = 0;
  for (int i = t; i < WPOOL; i += THREADS) sW[i] = 0.f;
  __syncthreads();
  stageA<32, 50, 4, FR1, true>(W1, sW, t);
  stageA<50, 30, 2, FR2, true>(W2, sW, t);
  stageA<30, 20, 2, FR3, true>(W3, sW, t);
  stageA<20, 15, 2, FR4, true>(W4, sW, t);
  stageA<15,  8, 1, FR5, false>(W5, sW, t);
  if (t < 50)                  { sW[VB1 + t] = b1[t]; sW[VS1 + t] = g1[t] * rden; sW[VE1 + t] = be1[t]; }
  else if (t >= 64 && t < 94)  { int i = t - 64;  sW[VB2 + i] = b2[i]; sW[VS2 + i] = g2[i] * rden; sW[VE2 + i] = be2[i]; }
  else if (t >= 128 && t < 148){ int i = t - 128; sW[VB3 + i] = b3[i]; sW[VS3 + i] = g3[i] * rden; sW[VE3 + i] = be3[i]; }
  else if (t >= 192 && t < 207){ sW[VB4 + (t - 192)] = b4[t - 192]; }
  else if (t >= 224 && t < 232){ sW[VB5 + (t - 224)] = b5[t - 224]; }
  __syncthreads();

  const int w = t >> 6, lane = t & 63;
  const int c = lane & 15, g = lane >> 4;
  const int labase = lane * 4;

  const int wrow0 = blockIdx.x * ROWS_PER_BLOCK + w * (TPW * 16);
  const float4 *xp = reinterpret_cast<const float4 *>(
      events + (size_t)(wrow0 + c) * 32 + g * 8);

  f32x4 aa[TPW];  // statically indexed (full unroll) -> stays in VGPRs

#pragma unroll
  for (int tt = 0; tt < TPW; ++tt) {
    // ---- X B-frag straight from global: col=batch, k=g*8+e ----
    float4 xa = xp[tt * 128], xb = xp[tt * 128 + 1];
    float xf[8] = {xa.x, xa.y, xa.z, xa.w, xb.x, xb.y, xb.z, xb.w};
    short8 Xh, Xl; pack8(xf, Xh, Xl);

    // ---- L1: 4 permuted out-tiles ----
    f32x4 a1[4];
#pragma unroll
    for (int ti = 0; ti < 4; ++ti) {
      f32x4 acc = ldv4(sW, VB1 + (ti >> 1) * 32 + g * 8 + (ti & 1) * 4);
      short8 wh = ldfrag(sW, FR1 + ti * 512 + labase);
      short8 wl = ldfrag(sW, FR1 + ti * 512 + 256 + labase);
      acc = mfma16(wh, Xl, acc);
      acc = mfma16(wl, Xh, acc);
      a1[ti] = mfma16(wh, Xh, acc);
    }

    // ---- L1 -> L2 B-frags (lane-local), K=64 = 2 kt ----
    short8 B2h[2], B2l[2];
    bnpack(a1[0], a1[1], sW, VS1,      VE1,      g, B2h[0], B2l[0]);
    bnpack(a1[2], a1[3], sW, VS1 + 32, VE1 + 32, g, B2h[1], B2l[1]);

    // ---- L2: 2 out-tiles x 2 kt ----
    f32x4 a2[2];
#pragma unroll
    for (int ti = 0; ti < 2; ++ti) {
      f32x4 acc = ldv4(sW, VB2 + g * 8 + ti * 4);
#pragma unroll
      for (int kt = 0; kt < 2; ++kt) {
        short8 wh = ldfrag(sW, FR2 + (kt * 2 + ti) * 512 + labase);
        short8 wl = ldfrag(sW, FR2 + (kt * 2 + ti) * 512 + 256 + labase);
        acc = mfma16(wh, B2l[kt], acc);
        acc = mfma16(wl, B2h[kt], acc);
        acc = mfma16(wh, B2h[kt], acc);
      }
      a2[ti] = acc;
    }

    // ---- L2 -> L3 ----
    short8 B3h, B3l;
    bnpack(a2[0], a2[1], sW, VS2, VE2, g, B3h, B3l);

    // ---- L3: 2 out-tiles ----
    f32x4 a3[2];
#pragma unroll
    for (int ti = 0; ti < 2; ++ti) {
      f32x4 acc = ldv4(sW, VB3 + g * 8 + ti * 4);
      short8 wh = ldfrag(sW, FR3 + ti * 512 + labase);
      short8 wl = ldfrag(sW, FR3 + ti * 512 + 256 + labase);
      acc = mfma16(wh, B3l, acc);
      acc = mfma16(wl, B3h, acc);
      a3[ti] = mfma16(wh, B3h, acc);
    }

    // ---- L3 -> L4 ----
    short8 B4h, B4l;
    bnpack(a3[0], a3[1], sW, VS3, VE3, g, B4h, B4l);

    // ---- L4: 2 out-tiles, ReLU ----
    f32x4 a4[2];
#pragma unroll
    for (int ti = 0; ti < 2; ++ti) {
      f32x4 acc = ldv4(sW, VB4 + g * 8 + ti * 4);
      short8 wh = ldfrag(sW, FR4 + ti * 512 + labase);
      short8 wl = ldfrag(sW, FR4 + ti * 512 + 256 + labase);
      acc = mfma16(wh, B4l, acc);
      acc = mfma16(wl, B4h, acc);
      a4[ti] = mfma16(wh, B4h, acc);
    }

    // ---- L4 -> L5 (ReLU only, no BN) ----
    short8 B5h, B5l;
    {
      float f[8];
#pragma unroll
      for (int q = 0; q < 4; ++q) {
        f[q]     = fmaxf(a4[0][q], 0.f);
        f[4 + q] = fmaxf(a4[1][q], 0.f);
      }
      pack8(f, B5h, B5l);
    }

    // ---- L5: identity col map -> lane holds logits g*4+q (g<2 real) ----
    {
      f32x4 acc = ldv4(sW, VB5 + g * 4);
      short8 wh = ldfrag(sW, FR5 + labase);
      short8 wl = ldfrag(sW, FR5 + 256 + labase);
      acc = mfma16(wh, B5l, acc);
      acc = mfma16(wl, B5h, acc);
      aa[tt] = mfma16(wh, B5h, acc);
    }
  }

  // ---- deferred epilogue: all TPW tiles' sampling batched ----
#pragma unroll
  for (int tt = 0; tt < TPW; ++tt) {
    const int row = wrow0 + tt * 16 + c;
    float s2v = __shfl_xor(aa[tt][2], 32);
    float s3v = __shfl_xor(aa[tt][3], 32);
    float l0 = (g < 2) ? aa[tt][0] : s2v;
    float l1 = (g < 2) ? aa[tt][1] : s3v;
    const int base = ((g & 1) << 2) | ((g >> 1) << 1);  // 0,4,2,6
    float p0 = 1.f / (1.f + __expf(-l0));
    float p1 = 1.f / (1.f + __expf(-l1));
    unsigned o0, o1, q0, q1;
    tf2x32(0u, 8u * (unsigned)row + (unsigned)base,      o0, o1);
    tf2x32(0u, 8u * (unsigned)row + (unsigned)base + 1u, q0, q1);
    float u0 = __uint_as_float(0x3F800000u | ((o0 ^ o1) >> 9)) - 1.f;
    float u1 = __uint_as_float(0x3F800000u | ((q0 ^ q1) >> 9)) - 1.f;
    float th0 = 1.f - p0, th1 = 1.f - p1;
    bool c0 = u0 < th0, c1 = u1 < th1;
    bool need = (fabsf(u0 - th0) < P_MARGIN) || (fabsf(u1 - th1) < P_MARGIN);
    float prod = (c0 ? th0 : p0) * (c1 ? th1 : p1);
    prod *= __shfl_xor(prod, 16);
    prod *= __shfl_xor(prod, 32);
    float2 chv = make_float2(c0 ? 0.f : 1.f, c1 ? 0.f : 1.f);
    *reinterpret_cast<float2 *>(out_chosen + (size_t)row * 8 + base) = chv;
    if (g == 0) out_logp[row] = __logf(prod);
    if (need) {  // dup rows possible (4 lanes/row) -> repair is idempotent
      unsigned i = atomicAdd(&s_cnt, 1u);
      if (i < FIXCAP) s_rows[i] = (unsigned)row;
    }
  }

  // ---- block-cooperative fp64 repair of flagged rows (overwrites) ----
  __syncthreads();
  unsigned cnt = s_cnt;
  if (cnt > FIXCAP) cnt = FIXCAP;
  if (cnt == 0) return;

  const double denom = sqrt(1.0 + 1e-5);
  for (unsigned r = 0; r < cnt; ++r) {  // cnt is block-uniform
    const int rb = (int)s_rows[r];

    if (t < 32) sA[t] = (double)events[(size_t)rb * 32 + t];
    __syncthreads();

    double v = 0.0;
    if (t < 50) {
#pragma unroll
      for (int k = 0; k < 32; ++k) v = fma(sA[k], (double)W1[k * 50 + t], v);
      v += (double)b1[t];
      v = v * ((double)g1[t] / denom) + (double)be1[t];
      v = v > 0.0 ? v : 0.0;
    }
    __syncthreads();
    if (t < 50) sB[t] = v;
    __syncthreads();

    v = 0.0;
    if (t < 30) {
#pragma unroll
      for (int k = 0; k < 50; ++k) v = fma(sB[k], (double)W2[k * 30 + t], v);
      v += (double)b2[t];
      v = v * ((double)g2[t] / denom) + (double)be2[t];
      v = v > 0.0 ? v : 0.0;
    }
    __syncthreads();
    if (t < 30) sA[t] = v;
    __syncthreads();

    v = 0.0;
    if (t < 20) {
#pragma unroll
      for (int k = 0; k < 30; ++k) v = fma(sA[k], (double)W3[k * 20 + t], v);
      v += (double)b3[t];
      v = v * ((double)g3[t] / denom) + (double)be3[t];
      v = v > 0.0 ? v : 0.0;
    }
    __syncthreads();
    if (t < 20) sB[t] = v;
    __syncthreads();

    v = 0.0;
    if (t < 15) {
#pragma unroll
      for (int k = 0; k < 20; ++k) v = fma(sB[k], (double)W4[k * 15 + t], v);
      v += (double)b4[t];
      v = v > 0.0 ? v : 0.0;
    }
    __syncthreads();
    if (t < 15) sA[t] = v;
    __syncthreads();

    if (t < 8) {
      v = 0.0;
#pragma unroll
      for (int k = 0; k < 15; ++k) v = fma(sA[k], (double)W5[k * 8 + t], v);
      v += (double)b5[t];
      double p = 1.0 / (1.0 + exp(-v));
      unsigned j = 8u * (unsigned)rb + (unsigned)t, o0, o1;
      tf2x32(0u, j, o0, o1);
      unsigned bits = o0 ^ o1;
      float u = __uint_as_float(0x3F800000u | (bits >> 9)) - 1.f;
      double thr = 1.0 - p;
      bool choice = ((double)u < thr);
      out_chosen[(size_t)rb * 8 + t] = choice ? 0.f : 1.f;
      sF[t] = choice ? thr : p;
    }
    __syncthreads();
    if (t == 0) {
      double prod = 1.0;
      for (int w2 = 0; w2 < 8; ++w2) prod *= sF[w2];
      out_logp[rb] = (float)log(prod);
    }
    __syncthreads();
  }
}

extern "C" void kernel_launch(void* const* d_in, const int* in_sizes, int n_in,
                              void* d_out, int out_size, void* d_ws, size_t ws_size,
                              hipStream_t stream) {
  const float* events = (const float*)d_in[0];
  const float* W1  = (const float*)d_in[1];
  const float* b1  = (const float*)d_in[2];
  const float* g1  = (const float*)d_in[3];
  const float* be1 = (const float*)d_in[4];
  const float* W2  = (const float*)d_in[5];
  const float* b2  = (const float*)d_in[6];
  const float* g2  = (const float*)d_in[7];
  const float* be2 = (const float*)d_in[8];
  const float* W3  = (const float*)d_in[9];
  const float* b3  = (const float*)d_in[10];
  const float* g3  = (const float*)d_in[11];
  const float* be3 = (const float*)d_in[12];
  const float* W4  = (const float*)d_in[13];
  const float* b4  = (const float*)d_in[14];
  const float* W5  = (const float*)d_in[15];
  const float* b5  = (const float*)d_in[16];

  const int B = in_sizes[0] / 32;  // 524288
  float* out = (float*)d_out;
  float* out_chosen = out;                   // (B, 8)
  float* out_logp   = out + (size_t)B * 8;   // (B,)

  const int blocks = (B + ROWS_PER_BLOCK - 1) / ROWS_PER_BLOCK;  // 2048
  hipLaunchKernelGGL(wtf_kernel, dim3(blocks), dim3(THREADS), 0, stream,
                     events, W1, b1, g1, be1, W2, b2, g2, be2,
                     W3, b3, g3, be3, W4, b4, W5, b5,
                     out_chosen, out_logp, B);
}